// Round 10
// baseline (134.915 us; speedup 1.0000x reference)
//
#include <hip/hip_runtime.h>
#include <math.h>

#define B_   16
#define N_   1024
#define DIM_ 128
#define H_   8
#define D_   16
#define BH_  128

typedef unsigned short u16;
typedef unsigned int   u32;
typedef __attribute__((ext_vector_type(8))) short short8;
typedef __attribute__((ext_vector_type(4))) float f32x4;

__device__ __forceinline__ float bf2f(u16 u) {
    union { u32 i; float f; } c; c.i = ((u32)u) << 16; return c.f;
}
__device__ __forceinline__ u16 f2bf(float f) {
    union { float f; u32 i; } c; c.f = f;
    u32 r = c.i + 0x7FFFu + ((c.i >> 16) & 1u);
    return (u16)(r >> 16);
}
// pack two positive f32 -> packed bf16 pair (round-half-up)
__device__ __forceinline__ u32 pack2bf(float a, float b) {
    union { float f; u32 i; } ca, cb; ca.f = a; cb.f = b;
    return ((ca.i + 0x8000u) >> 16) | ((cb.i + 0x8000u) & 0xFFFF0000u);
}
union frag8 { short8 s; u32 w[4]; };

// bf16 constants
#define BF_ONE  ((short)0x3F80)
#define BF_NINF ((u16)0xFF80)

// Q pre-scaled by 1/sqrt(DIM) * log2(e) so attn uses exp2 directly.
#define SCALE_L2E (0.08838834764831845f * 1.4426950408889634f)

// ---------------- Kernel 0: precision prep. x -> bf16 (same layout);
// Wqkv, Wout -> bf16 TRANSPOSED to [col][k] so GEMM B-frags are single b128
// loads (k-contiguous). Single-bf16 is enough: error budget analysis R9 —
// output absmax is dominated by the bf16 attn workspace (~1e-3), threshold 5e-3.
__global__ __launch_bounds__(256) void prep_kernel(
    const float* __restrict__ x, const float* __restrict__ Wqkv,
    const float* __restrict__ Wout,
    u16* __restrict__ xb, u16* __restrict__ wqkvb, u16* __restrict__ woutb)
{
    const int b = blockIdx.x, tid = threadIdx.x;
    if (b < 2048) {                         // x: 2M floats, 4 per thread
        const int i = b * 256 + tid;        // float4 index
        float4 v = ((const float4*)x)[i];
        ushort4 o = make_ushort4(f2bf(v.x), f2bf(v.y), f2bf(v.z), f2bf(v.w));
        *(ushort4*)(xb + (size_t)i * 4) = o;
    } else {                                // weights: 65536 elements total
        const int t = (b - 2048) * 256 + tid;
        if (t < 49152) {                    // Wqkv[k][col], k<128, col<384
            const int k = t / 384, col = t - k * 384;
            wqkvb[(size_t)col * 128 + k] = f2bf(Wqkv[t]);
        } else {
            const int t2 = t - 49152;       // Wout[k][col], 128x128
            const int k = t2 >> 7, col = t2 & 127;
            woutb[(size_t)col * 128 + k] = f2bf(Wout[t2]);
        }
    }
}

// ---------------- Kernel 1: qkv = xb @ Wqkvb, pure bf16 MFMA.
// A-frag and B-frag are each ONE b128 load (pre-transposed weights).
// K rows widened to 32 bf16: slots 0-15 = K values, slot 16 = mask bias
// (0 valid / -inf masked, log2 domain), 17-31 don't-care. Q pre-scaled.
__global__ __launch_bounds__(256) void qkv_kernel(
    const u16* __restrict__ xb, const u16* __restrict__ wqkvb,
    const float* __restrict__ maskp, const float* __restrict__ mapsp,
    u16* __restrict__ qws, u16* __restrict__ kws2, u16* __restrict__ vtws)
{
    const int tid  = threadIdx.x;
    const int wave = tid >> 6, lane = tid & 63;
    const int i16  = lane & 15, quad = lane >> 4;
    const int cb   = blockIdx.x % 6;          // 64-col block
    const int rb   = blockIdx.x / 6;          // 64-row block
    const int row_m = rb * 64 + wave * 16;    // wave's 16-row slice

    const u16* xp = xb + (size_t)(row_m + i16) * 128;
    const u16* wb = wqkvb + (size_t)(cb * 64 + i16) * 128;

    f32x4 acc0 = {0,0,0,0}, acc1 = {0,0,0,0}, acc2 = {0,0,0,0}, acc3 = {0,0,0,0};

    #pragma unroll
    for (int ks = 0; ks < 4; ks++) {
        const int k0 = ks * 32 + quad * 8;
        const short8 a = *(const short8*)(xp + k0);
        acc0 = __builtin_amdgcn_mfma_f32_16x16x32_bf16(
                   a, *(const short8*)(wb + k0), acc0, 0, 0, 0);
        acc1 = __builtin_amdgcn_mfma_f32_16x16x32_bf16(
                   a, *(const short8*)(wb + 16 * 128 + k0), acc1, 0, 0, 0);
        acc2 = __builtin_amdgcn_mfma_f32_16x16x32_bf16(
                   a, *(const short8*)(wb + 32 * 128 + k0), acc2, 0, 0, 0);
        acc3 = __builtin_amdgcn_mfma_f32_16x16x32_bf16(
                   a, *(const short8*)(wb + 48 * 128 + k0), acc3, 0, 0, 0);
    }

    // Epilogue. C/D layout: col = i16 (n-index), row = quad*4 + r.
    const int which = (cb * 64) >> 7;   // 0=Q 1=K 2=V
    const int row   = row_m + quad * 4;
    const int bb    = row >> 10, n = row & 1023;

    #define STORE_CT(CT, ACC) { \
        const int c  = (cb * 64 + CT * 16) & 127; \
        const int h  = c >> 4; \
        const int bh = bb * 8 + h; \
        const int dd = i16; \
        if (which == 0) { \
            u16* p = qws + ((size_t)(bh * N_ + n)) * 16 + dd; \
            p[0]  = f2bf(ACC[0] * SCALE_L2E); p[16] = f2bf(ACC[1] * SCALE_L2E); \
            p[32] = f2bf(ACC[2] * SCALE_L2E); p[48] = f2bf(ACC[3] * SCALE_L2E); \
        } else if (which == 1) { \
            u16* p = kws2 + ((size_t)(bh * N_ + n)) * 32 + dd; \
            p[0]  = f2bf(ACC[0]); p[32] = f2bf(ACC[1]); \
            p[64] = f2bf(ACC[2]); p[96] = f2bf(ACC[3]); \
            if (dd == 0) { \
                _Pragma("unroll") \
                for (int r = 0; r < 4; r++) { \
                    const int nr = n + r; \
                    const bool valid = (nr == 0) || \
                        (maskp[nr - 1] != 0.0f && mapsp[bb * (N_ - 1) + nr - 1] != 0.0f); \
                    kws2[((size_t)(bh * N_ + nr)) * 32 + 16] = valid ? (u16)0 : BF_NINF; \
                } \
            } \
        } else { \
            *(ushort4*)(vtws + ((size_t)(bh * 16 + dd)) * N_ + n) = \
                make_ushort4(f2bf(ACC[0]), f2bf(ACC[1]), f2bf(ACC[2]), f2bf(ACC[3])); \
        } }
    STORE_CT(0, acc0)
    STORE_CT(1, acc1)
    STORE_CT(2, acc2)
    STORE_CT(3, acc3)
    #undef STORE_CT
}

// ---------------- Kernel 2: attention, 4 q-tiles per wave, bias-in-K.
// (UNCHANGED from R9 — keeps the delta attributable to qkv/out/prep.)
__global__ __launch_bounds__(256) void attn_kernel(
    const u16* __restrict__ qws, const u16* __restrict__ kws2, const u16* __restrict__ vtws,
    u16* __restrict__ attn)
{
    const int tid  = threadIdx.x;
    const int wave = tid >> 6, lane = tid & 63;
    const int i16  = lane & 15, quad = lane >> 4;
    const int bh   = blockIdx.x;            // 0..127
    const int qb   = blockIdx.y;            // 0..3
    const int bb   = bh >> 3, h = bh & 7;
    const int qrow0 = qb * 256 + wave * 64; // wave's 64 q-rows (4 tiles of 16)
    const int perm = ((i16 & 12) << 1) | (i16 & 3);   // 8*(i16>>2)+(i16&3)

    const short8 zero8 = {0,0,0,0,0,0,0,0};
    const short8 ones8 = {BF_ONE,BF_ONE,BF_ONE,BF_ONE,BF_ONE,BF_ONE,BF_ONE,BF_ONE};

    short8 qf0 = zero8, qf1 = zero8, qf2 = zero8, qf3 = zero8;
    if (lane < 32) {           // quads 0,1: Q values (k = d in [0,16))
        const u16* qp = qws + ((size_t)(bh * N_ + qrow0 + i16)) * 16 + quad * 8;
        qf0 = *(const short8*)(qp);
        qf1 = *(const short8*)(qp + 256);
        qf2 = *(const short8*)(qp + 512);
        qf3 = *(const short8*)(qp + 768);
    } else if (lane < 48) {    // quad 2: k=16 -> 1.0 (bias lane)
        qf0[0] = BF_ONE; qf1[0] = BF_ONE; qf2[0] = BF_ONE; qf3[0] = BF_ONE;
    }                          // quad 3: zeros

    const u16* kpA = kws2 + ((size_t)(bh * N_ + perm)) * 32 + quad * 8;
    const u16* kpB = kpA + 4 * 32;
    const u16* vp  = vtws + ((size_t)(bh * 16 + i16)) * N_ + quad * 8;

    f32x4 o0 = {0,0,0,0}, o1 = {0,0,0,0}, o2 = {0,0,0,0}, o3 = {0,0,0,0};
    f32x4 l0 = {0,0,0,0}, l1 = {0,0,0,0}, l2 = {0,0,0,0}, l3 = {0,0,0,0};
    const f32x4 zc = {0.f, 0.f, 0.f, 0.f};

    #pragma unroll 2
    for (int j0 = 0; j0 < N_; j0 += 32) {
        const short8 kfA = *(const short8*)kpA;
        const short8 kfB = *(const short8*)kpB;
        const short8 vf  = *(const short8*)vp;
        kpA += 32 * 32; kpB += 32 * 32; vp += 32;

        #define TILE(QF, O, L) { \
            f32x4 stA = __builtin_amdgcn_mfma_f32_16x16x32_bf16(kfA, QF, zc, 0, 0, 0); \
            f32x4 stB = __builtin_amdgcn_mfma_f32_16x16x32_bf16(kfB, QF, zc, 0, 0, 0); \
            float pA0 = __builtin_amdgcn_exp2f(stA[0]); \
            float pA1 = __builtin_amdgcn_exp2f(stA[1]); \
            float pA2 = __builtin_amdgcn_exp2f(stA[2]); \
            float pA3 = __builtin_amdgcn_exp2f(stA[3]); \
            float pB0 = __builtin_amdgcn_exp2f(stB[0]); \
            float pB1 = __builtin_amdgcn_exp2f(stB[1]); \
            float pB2 = __builtin_amdgcn_exp2f(stB[2]); \
            float pB3 = __builtin_amdgcn_exp2f(stB[3]); \
            frag8 pk; \
            pk.w[0] = pack2bf(pA0, pA1); pk.w[1] = pack2bf(pA2, pA3); \
            pk.w[2] = pack2bf(pB0, pB1); pk.w[3] = pack2bf(pB2, pB3); \
            O = __builtin_amdgcn_mfma_f32_16x16x32_bf16(vf,    pk.s, O, 0, 0, 0); \
            L = __builtin_amdgcn_mfma_f32_16x16x32_bf16(ones8, pk.s, L, 0, 0, 0); \
        }
        TILE(qf0, o0, l0)
        TILE(qf1, o1, l1)
        TILE(qf2, o2, l2)
        TILE(qf3, o3, l3)
        #undef TILE
    }

    #define OUT_T(T, O, L) { \
        const float inv = 1.0f / L[0]; \
        ushort4 pko = make_ushort4(f2bf(O[0] * inv), f2bf(O[1] * inv), \
                                   f2bf(O[2] * inv), f2bf(O[3] * inv)); \
        *(ushort4*)(attn + ((size_t)(bb * N_ + qrow0 + T * 16 + i16)) * DIM_ \
                    + h * 16 + quad * 4) = pko; }
    OUT_T(0, o0, l0)
    OUT_T(1, o1, l1)
    OUT_T(2, o2, l2)
    OUT_T(3, o3, l3)
    #undef OUT_T
}

// ---------------- Kernel 3: out = attn @ Woutb + bout, pure bf16 MFMA.
__global__ __launch_bounds__(256) void out_kernel(
    const u16* __restrict__ attnw, const u16* __restrict__ woutb,
    const float* __restrict__ boutp, float* __restrict__ outp)
{
    const int tid  = threadIdx.x;
    const int wave = tid >> 6, lane = tid & 63;
    const int i16  = lane & 15, quad = lane >> 4;
    const int cb   = blockIdx.x & 1;          // 64-col block
    const int rb   = blockIdx.x >> 1;         // 64-row block
    const int row_m = rb * 64 + wave * 16;

    const u16* ap = attnw + (size_t)(row_m + i16) * 128;
    const u16* wb = woutb + (size_t)(cb * 64 + i16) * 128;

    f32x4 acc0 = {0,0,0,0}, acc1 = {0,0,0,0}, acc2 = {0,0,0,0}, acc3 = {0,0,0,0};

    #pragma unroll
    for (int ks = 0; ks < 4; ks++) {
        const int k0 = ks * 32 + quad * 8;
        const short8 a = *(const short8*)(ap + k0);
        acc0 = __builtin_amdgcn_mfma_f32_16x16x32_bf16(
                   a, *(const short8*)(wb + k0), acc0, 0, 0, 0);
        acc1 = __builtin_amdgcn_mfma_f32_16x16x32_bf16(
                   a, *(const short8*)(wb + 16 * 128 + k0), acc1, 0, 0, 0);
        acc2 = __builtin_amdgcn_mfma_f32_16x16x32_bf16(
                   a, *(const short8*)(wb + 32 * 128 + k0), acc2, 0, 0, 0);
        acc3 = __builtin_amdgcn_mfma_f32_16x16x32_bf16(
                   a, *(const short8*)(wb + 48 * 128 + k0), acc3, 0, 0, 0);
    }

    const int row = row_m + quad * 4;
    #define STORE_CT(CT, ACC) { \
        const int col = cb * 64 + CT * 16 + i16; \
        const float bo = boutp[col]; \
        float* op = outp + (size_t)row * 128 + col; \
        op[0 * 128] = ACC[0] + bo; \
        op[1 * 128] = ACC[1] + bo; \
        op[2 * 128] = ACC[2] + bo; \
        op[3 * 128] = ACC[3] + bo; \
    }
    STORE_CT(0, acc0)
    STORE_CT(1, acc1)
    STORE_CT(2, acc2)
    STORE_CT(3, acc3)
    #undef STORE_CT
}

extern "C" void kernel_launch(void* const* d_in, const int* in_sizes, int n_in,
                              void* d_out, int out_size, void* d_ws, size_t ws_size,
                              hipStream_t stream) {
    const float* x    = (const float*)d_in[0];
    const float* mask = (const float*)d_in[1];
    const float* maps = (const float*)d_in[2];
    const float* Wqkv = (const float*)d_in[3];
    const float* Wout = (const float*)d_in[4];
    const float* bout = (const float*)d_in[5];
    // ws (u16 units): Q 2M | K2 4M | Vt 2M | attn 2M | xb 2M | Wqkvb 48K | Woutb 16K
    u16* qws    = (u16*)d_ws;
    u16* kws2   = qws   + (size_t)2 * 1024 * 1024;
    u16* vtws   = kws2  + (size_t)4 * 1024 * 1024;
    u16* attn   = vtws  + (size_t)2 * 1024 * 1024;
    u16* xbws   = attn  + (size_t)2 * 1024 * 1024;
    u16* wqkvb  = xbws  + (size_t)2 * 1024 * 1024;
    u16* woutb  = wqkvb + (size_t)384 * 128;

    prep_kernel<<<dim3(2304), dim3(256), 0, stream>>>(x, Wqkv, Wout, xbws, wqkvb, woutb);
    qkv_kernel<<<dim3(1536), dim3(256), 0, stream>>>(xbws, wqkvb, mask, maps, qws, kws2, vtws);
    attn_kernel<<<dim3(128, 4), dim3(256), 0, stream>>>(qws, kws2, vtws, attn);
    out_kernel<<<dim3(512), dim3(256), 0, stream>>>(attn, woutb, bout, (float*)d_out);
}